// Round 2
// baseline (665.067 us; speedup 1.0000x reference)
//
#include <hip/hip_runtime.h>
#include <hip/hip_bf16.h>

typedef __hip_bfloat16 bf16;
typedef __attribute__((ext_vector_type(8))) short s16x8;   // 8 bf16 (4 VGPRs) MFMA frag
typedef __attribute__((ext_vector_type(4))) float f32x4;   // MFMA accumulator

#define B_ 2
#define S_ 4096
#define H_ 2048
#define R_ 2048
#define M_ 8192      // B*S
#define NB_ 16
#define BW_ 128
#define CHUNK 64     // scan chunk length
#define NCH 64       // S/CHUNK

__device__ __forceinline__ short f2b_s(float f) {
    return (short)__builtin_bit_cast(unsigned short, __float2bfloat16(f));
}
__device__ __forceinline__ float b2f_s(short s) {
    unsigned int u = ((unsigned int)(unsigned short)s) << 16;
    return __builtin_bit_cast(float, u);
}
__device__ __forceinline__ float sigm(float x) { return 1.f / (1.f + expf(-x)); }

// ---------------- cast fp32 -> bf16, 8 elems/thread ----------------
__global__ __launch_bounds__(256) void cast_f32_bf16(const float* __restrict__ in,
                                                     bf16* __restrict__ out, int n) {
    int idx = blockIdx.x * 256 + threadIdx.x;
    int i8 = idx * 8;
    if (i8 >= n) return;
    float4 v0 = *(const float4*)(in + i8);
    float4 v1 = *(const float4*)(in + i8 + 4);
    s16x8 o;
    o[0] = f2b_s(v0.x); o[1] = f2b_s(v0.y); o[2] = f2b_s(v0.z); o[3] = f2b_s(v0.w);
    o[4] = f2b_s(v1.x); o[5] = f2b_s(v1.y); o[6] = f2b_s(v1.z); o[7] = f2b_s(v1.w);
    *(s16x8*)(out + i8) = o;
}

// ---------------- generic NT GEMM: C[M,N] = A[M,K] * B[N,K]^T, bf16 in, OutT out ----
// 128x128 tile, BK=64, 4 waves 2x2, 64x64/wave, 16x16x32 MFMA, XOR-swizzled LDS.
__device__ __forceinline__ void store_c(float* p, float v) { *p = v; }
__device__ __forceinline__ void store_c(bf16* p, float v) { *p = __float2bfloat16(v); }

template <typename OutT>
__global__ __launch_bounds__(256) void gemm_bt(const bf16* __restrict__ A,
                                               const bf16* __restrict__ Bm,
                                               OutT* __restrict__ C,
                                               int K, int lda, int ldb, int ldc) {
    __shared__ __align__(16) short As[128 * 64];
    __shared__ __align__(16) short Bs[128 * 64];
    const int tid = threadIdx.x;
    const int lane = tid & 63, wave = tid >> 6;
    const int waveM = wave >> 1, waveN = wave & 1;
    const int mBase = blockIdx.y * 128, nBase = blockIdx.x * 128;
    const int fm = lane & 15, q = lane >> 4;

    f32x4 acc[4][4];
#pragma unroll
    for (int i = 0; i < 4; ++i)
#pragma unroll
        for (int j = 0; j < 4; ++j) acc[i][j] = (f32x4){0.f, 0.f, 0.f, 0.f};

    for (int k0 = 0; k0 < K; k0 += 64) {
        s16x8 av[4], bv[4];
#pragma unroll
        for (int it = 0; it < 4; ++it) {
            int off = it * 4096 + tid * 16;          // byte offset in tile
            int r = off >> 7;                        // row
            int g = ((off & 127) >> 4) ^ (r & 7);    // swizzled k-group
            av[it] = *(const s16x8*)(A + (size_t)(mBase + r) * lda + k0 + g * 8);
            bv[it] = *(const s16x8*)(Bm + (size_t)(nBase + r) * ldb + k0 + g * 8);
        }
        __syncthreads();
#pragma unroll
        for (int it = 0; it < 4; ++it) {
            int off = it * 4096 + tid * 16;
            *(s16x8*)((char*)As + off) = av[it];
            *(s16x8*)((char*)Bs + off) = bv[it];
        }
        __syncthreads();
#pragma unroll
        for (int s = 0; s < 2; ++s) {
            s16x8 af[4], bfr[4];
#pragma unroll
            for (int i = 0; i < 4; ++i) {
                int row = waveM * 64 + i * 16 + fm;
                af[i] = *(const s16x8*)((char*)As + row * 128 + ((((s << 2) + q) ^ (row & 7)) << 4));
                int col = waveN * 64 + i * 16 + fm;
                bfr[i] = *(const s16x8*)((char*)Bs + col * 128 + ((((s << 2) + q) ^ (col & 7)) << 4));
            }
#pragma unroll
            for (int i = 0; i < 4; ++i)
#pragma unroll
                for (int j = 0; j < 4; ++j)
                    acc[i][j] = __builtin_amdgcn_mfma_f32_16x16x32_bf16(af[i], bfr[j], acc[i][j], 0, 0, 0);
        }
    }
    // C/D layout: col=lane&15, row=q*4+reg (m89/m91-verified)
#pragma unroll
    for (int i = 0; i < 4; ++i) {
        int rowg = mBase + waveM * 64 + i * 16 + q * 4;
#pragma unroll
        for (int j = 0; j < 4; ++j) {
            int colg = nBase + waveN * 64 + j * 16 + fm;
#pragma unroll
            for (int rr = 0; rr < 4; ++rr)
                store_c(C + (size_t)(rowg + rr) * ldc + colg, acc[i][j][rr]);
        }
    }
}

// ---------------- causal depthwise conv: xc[m,r] = b[r] + sum_i w[i,r]*xr[m-3+i, r] ----
__global__ __launch_bounds__(256) void conv_kernel(const bf16* __restrict__ xr,
                                                   const float* __restrict__ cw,
                                                   const float* __restrict__ cb,
                                                   bf16* __restrict__ xc) {
    int idx = blockIdx.x * 256 + threadIdx.x;   // over M_*R_
    int r = idx & (R_ - 1);
    int m = idx >> 11;
    int t = m & (S_ - 1);
    float v = cb[r];
    const bf16* base = xr + (size_t)m * R_ + r;
#pragma unroll
    for (int i = 0; i < 4; ++i) {
        int tt = t - 3 + i;
        if (tt >= 0) v += cw[i * R_ + r] * __bfloat162float(base[(ptrdiff_t)(i - 3) * R_]);
    }
    xc[idx] = __float2bfloat16(v);
}

// ---------------- block-diag dual gate GEMM + RG-LRU pointwise epilogue ----------------
// grid (NB_, M_/128). K=128 in one LDS stage. Computes both gate pre-activations and
// writes a = exp(log_a) (fp32) and nx = xc*sigmoid(xg)*sqrt(-expm1(2 log_a)) (bf16).
__global__ __launch_bounds__(256) void gate_kernel(const bf16* __restrict__ xc,
                                                   const float* __restrict__ igw,
                                                   const float* __restrict__ igb,
                                                   const float* __restrict__ agw,
                                                   const float* __restrict__ agb,
                                                   const float* __restrict__ apar,
                                                   float* __restrict__ a_out,
                                                   bf16* __restrict__ nx_out) {
    __shared__ __align__(16) short As[128 * 128];  // 32 KB A tile (rows m, k), swizzled
    __shared__ __align__(16) short Ws[128 * 128];  // 32 KB weight tile [n_out][k]
    const int n = blockIdx.x;
    const int mBase = blockIdx.y * 128;
    const int tid = threadIdx.x;
    const int lane = tid & 63, wave = tid >> 6;
    const int fm = lane & 15, q = lane >> 4;

    // stage A: 128 rows x 128 k bf16; row len 256B = 16 groups; swizzle g ^= (row&15)
#pragma unroll
    for (int it = 0; it < 8; ++it) {
        int off = it * 4096 + tid * 16;
        int r = off >> 8;
        int g = ((off & 255) >> 4) ^ (r & 15);
        *(s16x8*)((char*)As + off) =
            *(const s16x8*)(xc + (size_t)(mBase + r) * R_ + n * BW_ + g * 8);
    }
    const int j = tid & 127, half = tid >> 7;

    f32x4 accI[2][8], accA[2][8];
#pragma unroll
    for (int i = 0; i < 2; ++i)
#pragma unroll
        for (int jj = 0; jj < 8; ++jj) {
            accI[i][jj] = (f32x4){0.f, 0.f, 0.f, 0.f};
            accA[i][jj] = (f32x4){0.f, 0.f, 0.f, 0.f};
        }

    for (int pass = 0; pass < 2; ++pass) {
        const float* w = pass == 0 ? igw : agw;
        if (pass == 1) __syncthreads();  // protect Ws reuse
        // stage W transposed: Ws[j][i] = w[n][i][j], bf16, swizzled
#pragma unroll
        for (int it = 0; it < 8; ++it) {
            int i0 = (it * 2 + half) * 8;
            s16x8 wv;
#pragma unroll
            for (int u = 0; u < 8; ++u)
                wv[u] = f2b_s(w[n * 16384 + (i0 + u) * 128 + j]);
            *(s16x8*)((char*)Ws + j * 256 + ((((i0 >> 3)) ^ (j & 15)) << 4)) = wv;
        }
        __syncthreads();
#pragma unroll
        for (int s = 0; s < 4; ++s) {
            s16x8 af[2];
#pragma unroll
            for (int i = 0; i < 2; ++i) {
                int row = wave * 32 + i * 16 + fm;
                af[i] = *(const s16x8*)((char*)As + row * 256 + ((((s << 2) + q) ^ (row & 15)) << 4));
            }
#pragma unroll
            for (int jj = 0; jj < 8; ++jj) {
                int wrow = jj * 16 + fm;
                s16x8 bw = *(const s16x8*)((char*)Ws + wrow * 256 + ((((s << 2) + q) ^ (wrow & 15)) << 4));
                if (pass == 0) {
                    accI[0][jj] = __builtin_amdgcn_mfma_f32_16x16x32_bf16(af[0], bw, accI[0][jj], 0, 0, 0);
                    accI[1][jj] = __builtin_amdgcn_mfma_f32_16x16x32_bf16(af[1], bw, accI[1][jj], 0, 0, 0);
                } else {
                    accA[0][jj] = __builtin_amdgcn_mfma_f32_16x16x32_bf16(af[0], bw, accA[0][jj], 0, 0, 0);
                    accA[1][jj] = __builtin_amdgcn_mfma_f32_16x16x32_bf16(af[1], bw, accA[1][jj], 0, 0, 0);
                }
            }
        }
    }
    // epilogue: C/D col=lane&15(=fm), row=q*4+rr. xc value re-read from LDS As.
#pragma unroll
    for (int i = 0; i < 2; ++i) {
        int rowl = wave * 32 + i * 16 + q * 4;      // tile-local row
#pragma unroll
        for (int jj = 0; jj < 8; ++jj) {
            int col = jj * 16 + fm;                 // channel within block
            int r = n * BW_ + col;
            float bi = igb[r], ba = agb[r];
            float sp = log1pf(expf(apar[r]));       // softplus(a_param)
#pragma unroll
            for (int rr = 0; rr < 4; ++rr) {
                int row = rowl + rr;
                float xcv = b2f_s(*(const short*)((char*)As + row * 256 +
                                  ((((col >> 3)) ^ (row & 15)) << 4) + (col & 7) * 2));
                float xg = accI[i][jj][rr] + bi;
                float ag = accA[i][jj][rr] + ba;
                float la = -8.f * sigm(ag) * sp;
                float av = expf(la);
                float mult = sqrtf(-expm1f(2.f * la));
                size_t o = (size_t)(mBase + row) * R_ + r;
                a_out[o] = av;
                nx_out[o] = __float2bfloat16(xcv * sigm(xg) * mult);
            }
        }
    }
}

// ---------------- chunked RG-LRU scan ----------------
// pass1: within-chunk scan. In-place: a_buf <- cumprod(a) (fp32), nx_buf <- h_local (bf16).
__global__ __launch_bounds__(256) void scan_pass1(float* __restrict__ a_buf,
                                                  bf16* __restrict__ nx_buf,
                                                  float* __restrict__ Ach,
                                                  float* __restrict__ Hla) {
    int bid = blockIdx.x;                 // B*NCH*8 = 1024
    int rt = bid & 7, c = (bid >> 3) & 63, b = bid >> 9;
    int r = rt * 256 + threadIdx.x;
    size_t base = ((size_t)(b * S_ + c * CHUNK)) * R_ + r;
    float h = 0.f, cum = 1.f;
    for (int t = 0; t < CHUNK; ++t) {
        size_t o = base + (size_t)t * R_;
        float a = a_buf[o];
        float nx = __bfloat162float(nx_buf[o]);
        h = fmaf(a, h, nx);
        cum *= a;
        a_buf[o] = cum;
        nx_buf[o] = __float2bfloat16(h);
    }
    int so = (b * NCH + c) * R_ + r;
    Ach[so] = cum;
    Hla[so] = h;   // fp32 chunk-final h (carry path stays fp32)
}

// pass2: carry into each chunk (sequential over 64 chunks, fp32)
__global__ __launch_bounds__(256) void scan_carry(const float* __restrict__ Ach,
                                                  const float* __restrict__ Hla,
                                                  float* __restrict__ carry) {
    int idx = blockIdx.x * 256 + threadIdx.x;  // B*R
    int r = idx & (R_ - 1), b = idx >> 11;
    float cy = 0.f;
    for (int c = 0; c < NCH; ++c) {
        int o = (b * NCH + c) * R_ + r;
        carry[o] = cy;
        cy = fmaf(Ach[o], cy, Hla[o]);
    }
}

// pass3: h = h_local + carry*cum_a ; g = gelu_exact(y)*h -> bf16
__global__ __launch_bounds__(256) void pass3_g(const bf16* __restrict__ h_local,
                                               const float* __restrict__ cum_a,
                                               const float* __restrict__ carry,
                                               const bf16* __restrict__ yb,
                                               bf16* __restrict__ g_out) {
    int idx = blockIdx.x * 256 + threadIdx.x;  // M_*R_
    int r = idx & (R_ - 1), m = idx >> 11;
    int t = m & (S_ - 1), b = m >> 12;
    int c = t >> 6;
    float h = fmaf(carry[(b * NCH + c) * R_ + r], cum_a[idx],
                   __bfloat162float(h_local[idx]));
    float y = __bfloat162float(yb[idx]);
    float g = 0.5f * y * (1.f + erff(y * 0.70710678118654752f));
    g_out[idx] = __float2bfloat16(g * h);
}

extern "C" void kernel_launch(void* const* d_in, const int* in_sizes, int n_in,
                              void* d_out, int out_size, void* d_ws, size_t ws_size,
                              hipStream_t stream) {
    const float* x    = (const float*)d_in[0];
    const float* Wxy  = (const float*)d_in[1];
    const float* igw  = (const float*)d_in[2];
    const float* igb  = (const float*)d_in[3];
    const float* agw  = (const float*)d_in[4];
    const float* agb  = (const float*)d_in[5];
    const float* apar = (const float*)d_in[6];
    const float* cw   = (const float*)d_in[7];
    const float* cb   = (const float*)d_in[8];
    const float* Wres = (const float*)d_in[9];
    float* out = (float*)d_out;

    // Workspace layout (187 MiB total), with lifetime overlays:
    //   [0,32)    xbf  bf16 [M,H]      (dead after GEMM1b)   }  overlaid by
    //   [32,64)   xr   bf16 [M,R]      (dead after conv)     }  abuf fp32 [M,R] at [0,64)
    //   [64,80)   wxyb bf16 [2R,H]
    //   [80,88)   wresb bf16 [H,R]
    //   [88,120)  y    bf16 [M,R]
    //   [120,152) xc   bf16 [M,R]      (dead after gate)     -> g bf16 (pass3 output)
    //   [152,184) nx   bf16 [M,R]      -> h_local (in place, scan_pass1)
    //   [184,187) Ach/Hla/carry fp32, 1 MiB each
    char* ws = (char*)d_ws;
    const size_t MiB = (size_t)1 << 20;
    bf16*  xbf   = (bf16*)(ws);
    bf16*  xr    = (bf16*)(ws + 32 * MiB);
    bf16*  wxyb  = (bf16*)(ws + 64 * MiB);
    bf16*  wresb = (bf16*)(ws + 80 * MiB);
    bf16*  yb    = (bf16*)(ws + 88 * MiB);
    bf16*  xc    = (bf16*)(ws + 120 * MiB);
    bf16*  g     = xc;                        // overlay
    float* abuf  = (float*)(ws);              // overlay on xbf+xr
    bf16*  nx    = (bf16*)(ws + 152 * MiB);
    float* Ach   = (float*)(ws + 184 * MiB);
    float* Hla   = (float*)(ws + 185 * MiB);
    float* cyb   = (float*)(ws + 186 * MiB);

    // casts to bf16
    cast_f32_bf16<<<8192, 256, 0, stream>>>(x, xbf, M_ * H_);
    cast_f32_bf16<<<4096, 256, 0, stream>>>(Wxy, wxyb, 2 * R_ * H_);
    cast_f32_bf16<<<2048, 256, 0, stream>>>(Wres, wresb, H_ * R_);

    // GEMM1 split: xr = x*Wxy[0:R]^T ; y = x*Wxy[R:2R]^T
    gemm_bt<bf16><<<dim3(16, 64), 256, 0, stream>>>(xbf, wxyb, xr, 2048, 2048, 2048, 2048);
    gemm_bt<bf16><<<dim3(16, 64), 256, 0, stream>>>(xbf, wxyb + (size_t)R_ * H_, yb,
                                                    2048, 2048, 2048, 2048);

    // causal conv -> xc bf16   (xr dead after this)
    conv_kernel<<<65536, 256, 0, stream>>>(xr, cw, cb, xc);

    // block-diag gates -> a (fp32, overlays xbf+xr), nx (bf16)
    gate_kernel<<<dim3(NB_, 64), 256, 0, stream>>>(xc, igw, igb, agw, agb, apar, abuf, nx);

    // chunked scan: pass1 in-place, carry, pass3 -> g (overlays xc)
    scan_pass1<<<1024, 256, 0, stream>>>(abuf, nx, Ach, Hla);
    scan_carry<<<16, 256, 0, stream>>>(Ach, Hla, cyb);
    pass3_g<<<65536, 256, 0, stream>>>(nx, abuf, cyb, yb, g);

    // GEMM2: out[M,H] = g[M,R] * Wres[H,R]^T  (fp32 out)
    gemm_bt<float><<<dim3(16, 64), 256, 0, stream>>>(g, wresb, out, 2048, 2048, 2048, 2048);
}

// Round 3
// 576.015 us; speedup vs baseline: 1.1546x; 1.1546x over previous
//
#include <hip/hip_runtime.h>
#include <hip/hip_bf16.h>

typedef __hip_bfloat16 bf16;
typedef __attribute__((ext_vector_type(8))) short s16x8;   // 8 bf16 (4 VGPRs) MFMA frag
typedef __attribute__((ext_vector_type(4))) float f32x4;   // MFMA accumulator

#define B_ 2
#define S_ 4096
#define H_ 2048
#define R_ 2048
#define M_ 8192      // B*S
#define NB_ 16
#define BW_ 128
#define CHUNK 64     // scan chunk length
#define NCH 64       // S/CHUNK

__device__ __forceinline__ short f2b_s(float f) {
    return (short)__builtin_bit_cast(unsigned short, __float2bfloat16(f));
}
__device__ __forceinline__ float b2f_s(short s) {
    unsigned int u = ((unsigned int)(unsigned short)s) << 16;
    return __builtin_bit_cast(float, u);
}
__device__ __forceinline__ float sigm_fast(float x) { return 1.f / (1.f + __expf(-x)); }

// async global->LDS, 16B per lane; LDS dest must be wave-uniform base + lane*16
__device__ __forceinline__ void async_g2l(const void* g, void* l) {
    __builtin_amdgcn_global_load_lds((const __attribute__((address_space(1))) void*)g,
                                     (__attribute__((address_space(3))) void*)l, 16, 0, 0);
}

// ---------------- cast fp32 -> bf16, 8 elems/thread ----------------
__global__ __launch_bounds__(256) void cast_f32_bf16(const float* __restrict__ in,
                                                     bf16* __restrict__ out, int n) {
    int idx = blockIdx.x * 256 + threadIdx.x;
    int i8 = idx * 8;
    if (i8 >= n) return;
    float4 v0 = *(const float4*)(in + i8);
    float4 v1 = *(const float4*)(in + i8 + 4);
    s16x8 o;
    o[0] = f2b_s(v0.x); o[1] = f2b_s(v0.y); o[2] = f2b_s(v0.z); o[3] = f2b_s(v0.w);
    o[4] = f2b_s(v1.x); o[5] = f2b_s(v1.y); o[6] = f2b_s(v1.z); o[7] = f2b_s(v1.w);
    *(s16x8*)(out + i8) = o;
}

// ---------------- transpose-cast gate weights: wT[p][n][j][i] = w_p[n][i][j] ----------
__global__ __launch_bounds__(256) void wcast_T(const float* __restrict__ igw,
                                               const float* __restrict__ agw,
                                               bf16* __restrict__ wT) {
    int idx = blockIdx.x * 256 + threadIdx.x;   // 0 .. 2*NB*128*128
    int p = idx >> 18;
    int rem = idx & 262143;
    int n = rem >> 14;
    int ji = rem & 16383;
    int j = ji >> 7, i = ji & 127;
    const float* w = p ? agw : igw;
    wT[idx] = __float2bfloat16(w[(n << 14) + (i << 7) + j]);
}

// ---------------- sp8[r] = 8*softplus(a_param[r]) ----------------
__global__ __launch_bounds__(256) void sp8_kernel(const float* __restrict__ apar,
                                                  float* __restrict__ sp8) {
    int r = blockIdx.x * 256 + threadIdx.x;
    float ap = apar[r];
    sp8[r] = 8.f * (ap > 20.f ? ap : log1pf(expf(ap)));
}

// ---------------- generic NT GEMM: C[M,N] = A[M,K] * B[N,K]^T, bf16 in, OutT out ----
// 128x128 tile, BK=64, 4 waves 2x2, 64x64/wave, 16x16x32 MFMA, XOR-swizzled LDS,
// global_load_lds width=16 staging (m97 structure).
__device__ __forceinline__ void store_c(float* p, float v) { *p = v; }
__device__ __forceinline__ void store_c(bf16* p, float v) { *p = __float2bfloat16(v); }

template <typename OutT>
__global__ __launch_bounds__(256) void gemm_bt(const bf16* __restrict__ A,
                                               const bf16* __restrict__ Bm,
                                               OutT* __restrict__ C,
                                               int K, int lda, int ldb, int ldc) {
    __shared__ __align__(16) short As[128 * 64];
    __shared__ __align__(16) short Bs[128 * 64];
    const int tid = threadIdx.x;
    const int lane = tid & 63, wave = tid >> 6;
    const int waveM = wave >> 1, waveN = wave & 1;
    const int mBase = blockIdx.y * 128, nBase = blockIdx.x * 128;
    const int fm = lane & 15, q = lane >> 4;

    f32x4 acc[4][4];
#pragma unroll
    for (int i = 0; i < 4; ++i)
#pragma unroll
        for (int j = 0; j < 4; ++j) acc[i][j] = (f32x4){0.f, 0.f, 0.f, 0.f};

    for (int k0 = 0; k0 < K; k0 += 64) {
        __syncthreads();
#pragma unroll
        for (int it = 0; it < 4; ++it) {
            int off = it * 4096 + tid * 16;          // byte offset in tile (lane-contig)
            int r = off >> 7;                        // row
            int g = ((off & 127) >> 4) ^ (r & 7);    // source k-group for this slot
            async_g2l(A + (size_t)(mBase + r) * lda + k0 + g * 8, (char*)As + off);
            async_g2l(Bm + (size_t)(nBase + r) * ldb + k0 + g * 8, (char*)Bs + off);
        }
        __syncthreads();
#pragma unroll
        for (int s = 0; s < 2; ++s) {
            s16x8 af[4], bfr[4];
#pragma unroll
            for (int i = 0; i < 4; ++i) {
                int row = waveM * 64 + i * 16 + fm;
                af[i] = *(const s16x8*)((char*)As + row * 128 + ((((s << 2) + q) ^ (row & 7)) << 4));
                int col = waveN * 64 + i * 16 + fm;
                bfr[i] = *(const s16x8*)((char*)Bs + col * 128 + ((((s << 2) + q) ^ (col & 7)) << 4));
            }
#pragma unroll
            for (int i = 0; i < 4; ++i)
#pragma unroll
                for (int j = 0; j < 4; ++j)
                    acc[i][j] = __builtin_amdgcn_mfma_f32_16x16x32_bf16(af[i], bfr[j], acc[i][j], 0, 0, 0);
        }
    }
    // C/D layout: col=lane&15, row=q*4+reg (m89/m91-verified)
#pragma unroll
    for (int i = 0; i < 4; ++i) {
        int rowg = mBase + waveM * 64 + i * 16 + q * 4;
#pragma unroll
        for (int j = 0; j < 4; ++j) {
            int colg = nBase + waveN * 64 + j * 16 + fm;
#pragma unroll
            for (int rr = 0; rr < 4; ++rr)
                store_c(C + (size_t)(rowg + rr) * ldc + colg, acc[i][j][rr]);
        }
    }
}

// ---------------- causal depthwise conv: xc[m,r] = b[r] + sum_i w[i,r]*xr[m-3+i, r] ----
__global__ __launch_bounds__(256) void conv_kernel(const bf16* __restrict__ xr,
                                                   const float* __restrict__ cw,
                                                   const float* __restrict__ cb,
                                                   bf16* __restrict__ xc) {
    int idx = blockIdx.x * 256 + threadIdx.x;   // over M_*R_
    int r = idx & (R_ - 1);
    int m = idx >> 11;
    int t = m & (S_ - 1);
    float v = cb[r];
    const bf16* base = xr + (size_t)m * R_ + r;
#pragma unroll
    for (int i = 0; i < 4; ++i) {
        int tt = t - 3 + i;
        if (tt >= 0) v += cw[i * R_ + r] * __bfloat162float(base[(ptrdiff_t)(i - 3) * R_]);
    }
    xc[idx] = __float2bfloat16(v);
}

// ---------------- block-diag dual gate GEMM + RG-LRU pointwise epilogue ----------------
// grid (NB_, M_/64). 64-row m-tile, K=128 single stage. Writes a = exp(log_a) (fp32)
// and nx = xc*sigmoid(xg)*sqrt(-expm1(2 log_a)) (bf16).
__global__ __launch_bounds__(256) void gate_kernel(const bf16* __restrict__ xc,
                                                   const bf16* __restrict__ wT,
                                                   const float* __restrict__ igb,
                                                   const float* __restrict__ agb,
                                                   const float* __restrict__ sp8,
                                                   float* __restrict__ a_out,
                                                   bf16* __restrict__ nx_out) {
    __shared__ __align__(16) short As[64 * 128];   // 16 KB, swizzled rows of 256B
    __shared__ __align__(16) short Ws[128 * 128];  // 32 KB, re-staged per gate
    const int n = blockIdx.x;
    const int mBase = blockIdx.y * 64;
    const int tid = threadIdx.x;
    const int lane = tid & 63, wave = tid >> 6;
    const int fm = lane & 15, q = lane >> 4;

    // stage A async: 64 rows x 128 k; slot group gs holds global group gs^(r&15)
#pragma unroll
    for (int it = 0; it < 4; ++it) {
        int off = it * 4096 + tid * 16;
        int r = off >> 8;
        int g = ((off & 255) >> 4) ^ (r & 15);
        async_g2l(xc + (size_t)(mBase + r) * R_ + n * BW_ + g * 8, (char*)As + off);
    }
    // stage Ws for input gate
    const bf16* w0 = wT + (size_t)n * 16384;
#pragma unroll
    for (int it = 0; it < 8; ++it) {
        int off = it * 4096 + tid * 16;
        int j = off >> 8;
        int g = ((off & 255) >> 4) ^ (j & 15);
        async_g2l(w0 + j * 128 + g * 8, (char*)Ws + off);
    }
    __syncthreads();

    f32x4 accI[8], accA[8];
#pragma unroll
    for (int jj = 0; jj < 8; ++jj) {
        accI[jj] = (f32x4){0.f, 0.f, 0.f, 0.f};
        accA[jj] = (f32x4){0.f, 0.f, 0.f, 0.f};
    }

    const int row = wave * 16 + fm;
#pragma unroll
    for (int s = 0; s < 4; ++s) {
        s16x8 af = *(const s16x8*)((char*)As + row * 256 + ((((s << 2) + q) ^ (row & 15)) << 4));
#pragma unroll
        for (int jj = 0; jj < 8; ++jj) {
            int wrow = jj * 16 + fm;
            s16x8 bw = *(const s16x8*)((char*)Ws + wrow * 256 + ((((s << 2) + q) ^ (wrow & 15)) << 4));
            accI[jj] = __builtin_amdgcn_mfma_f32_16x16x32_bf16(af, bw, accI[jj], 0, 0, 0);
        }
    }
    __syncthreads();  // all waves done reading Ws
    // stage Ws for a gate
    const bf16* w1 = wT + (size_t)(NB_ + n) * 16384;
#pragma unroll
    for (int it = 0; it < 8; ++it) {
        int off = it * 4096 + tid * 16;
        int j = off >> 8;
        int g = ((off & 255) >> 4) ^ (j & 15);
        async_g2l(w1 + j * 128 + g * 8, (char*)Ws + off);
    }
    __syncthreads();
#pragma unroll
    for (int s = 0; s < 4; ++s) {
        s16x8 af = *(const s16x8*)((char*)As + row * 256 + ((((s << 2) + q) ^ (row & 15)) << 4));
#pragma unroll
        for (int jj = 0; jj < 8; ++jj) {
            int wrow = jj * 16 + fm;
            s16x8 bw = *(const s16x8*)((char*)Ws + wrow * 256 + ((((s << 2) + q) ^ (wrow & 15)) << 4));
            accA[jj] = __builtin_amdgcn_mfma_f32_16x16x32_bf16(af, bw, accA[jj], 0, 0, 0);
        }
    }

    // epilogue: C/D col=fm, row=q*4+rr (tile-local rows 0..63)
#pragma unroll
    for (int jj = 0; jj < 8; ++jj) {
        int col = jj * 16 + fm;
        int r = n * BW_ + col;
        float bi = igb[r], ba = agb[r];
        float s8 = sp8[r];
#pragma unroll
        for (int rr = 0; rr < 4; ++rr) {
            int rowl = wave * 16 + q * 4 + rr;
            float xcv = b2f_s(*(const short*)((char*)As + rowl * 256 +
                              ((((col >> 3)) ^ (rowl & 15)) << 4) + (col & 7) * 2));
            float xg = accI[jj][rr] + bi;
            float ag = accA[jj][rr] + ba;
            float la = -s8 * sigm_fast(ag);
            float av = __expf(la);
            float t2 = 2.f * la;
            // -expm1(t2): Taylor for small |t2| (cancellation-safe), else 1 - a^2
            float nem = (t2 > -0.125f)
                ? -t2 * (1.f + t2 * (0.5f + t2 * (0.16666667f + t2 * 0.04166667f)))
                : 1.f - av * av;
            float mult = sqrtf(nem);
            size_t o = (size_t)(mBase + rowl) * R_ + r;
            a_out[o] = av;
            nx_out[o] = __float2bfloat16(xcv * sigm_fast(xg) * mult);
        }
    }
}

// ---------------- chunked RG-LRU scan ----------------
// passA: chunk summaries only (no in-place rewrite)
__global__ __launch_bounds__(256) void scan_passA(const float* __restrict__ a_buf,
                                                  const bf16* __restrict__ nx_buf,
                                                  float* __restrict__ Ach,
                                                  float* __restrict__ Hla) {
    int bid = blockIdx.x;                 // B*NCH*8 = 1024
    int rt = bid & 7, c = (bid >> 3) & 63, b = bid >> 9;
    int r = rt * 256 + threadIdx.x;
    size_t base = ((size_t)(b * S_ + c * CHUNK)) * R_ + r;
    float h = 0.f, cum = 1.f;
    for (int t = 0; t < CHUNK; ++t) {
        size_t o = base + (size_t)t * R_;
        float a = a_buf[o];
        float nx = __bfloat162float(nx_buf[o]);
        h = fmaf(a, h, nx);
        cum *= a;
    }
    int so = (b * NCH + c) * R_ + r;
    Ach[so] = cum;
    Hla[so] = h;
}

// carry into each chunk (sequential over 64 chunks, fp32)
__global__ __launch_bounds__(256) void scan_carry(const float* __restrict__ Ach,
                                                  const float* __restrict__ Hla,
                                                  float* __restrict__ carry) {
    int idx = blockIdx.x * 256 + threadIdx.x;  // B*R
    int r = idx & (R_ - 1), b = idx >> 11;
    float cy = 0.f;
    for (int c = 0; c < NCH; ++c) {
        int o = (b * NCH + c) * R_ + r;
        carry[o] = cy;
        cy = fmaf(Ach[o], cy, Hla[o]);
    }
}

// passB: re-run recurrence with carry folded in; g = gelu_exact(y)*h -> bf16
__global__ __launch_bounds__(256) void scan_passB(const float* __restrict__ a_buf,
                                                  const bf16* __restrict__ nx_buf,
                                                  const float* __restrict__ carry,
                                                  const bf16* __restrict__ yb,
                                                  bf16* __restrict__ g_out) {
    int bid = blockIdx.x;                 // B*NCH*8 = 1024
    int rt = bid & 7, c = (bid >> 3) & 63, b = bid >> 9;
    int r = rt * 256 + threadIdx.x;
    size_t base = ((size_t)(b * S_ + c * CHUNK)) * R_ + r;
    int so = (b * NCH + c) * R_ + r;
    float h = carry[so];
    for (int t = 0; t < CHUNK; ++t) {
        size_t o = base + (size_t)t * R_;
        float a = a_buf[o];
        float nx = __bfloat162float(nx_buf[o]);
        h = fmaf(a, h, nx);
        float y = __bfloat162float(yb[o]);
        float g = 0.5f * y * (1.f + erff(y * 0.70710678f));
        g_out[o] = __float2bfloat16(g * h);
    }
}

extern "C" void kernel_launch(void* const* d_in, const int* in_sizes, int n_in,
                              void* d_out, int out_size, void* d_ws, size_t ws_size,
                              hipStream_t stream) {
    const float* x    = (const float*)d_in[0];
    const float* Wxy  = (const float*)d_in[1];
    const float* igw  = (const float*)d_in[2];
    const float* igb  = (const float*)d_in[3];
    const float* agw  = (const float*)d_in[4];
    const float* agb  = (const float*)d_in[5];
    const float* apar = (const float*)d_in[6];
    const float* cw   = (const float*)d_in[7];
    const float* cb   = (const float*)d_in[8];
    const float* Wres = (const float*)d_in[9];
    float* out = (float*)d_out;

    // Workspace layout (187 MiB total), lifetime overlays:
    //   [0,32)    xbf  bf16 [M,H]   (dead after GEMM1b)  } overlaid by abuf fp32 [M,R]
    //   [32,64)   xr   bf16 [M,R]   (dead after conv)    }
    //   [64,80)   wxyb bf16 (dead after GEMM1b) -> wT (1 MiB) + sp8 staged after
    //   [80,88)   wresb bf16
    //   [88,120)  y    bf16 [M,R]
    //   [120,152) xc   bf16 [M,R]  (dead after gate) -> g bf16 (passB output)
    //   [152,184) nx   bf16 [M,R]
    //   [184,187) Ach/Hla/carry fp32, 1 MiB each
    char* ws = (char*)d_ws;
    const size_t MiB = (size_t)1 << 20;
    bf16*  xbf   = (bf16*)(ws);
    bf16*  xr    = (bf16*)(ws + 32 * MiB);
    bf16*  wxyb  = (bf16*)(ws + 64 * MiB);
    bf16*  wT    = (bf16*)(ws + 64 * MiB);    // overlay (staged after GEMM1b)
    float* sp8   = (float*)(ws + 65 * MiB);   // 8 KiB
    bf16*  wresb = (bf16*)(ws + 80 * MiB);
    bf16*  yb    = (bf16*)(ws + 88 * MiB);
    bf16*  xc    = (bf16*)(ws + 120 * MiB);
    bf16*  g     = xc;                        // overlay
    float* abuf  = (float*)(ws);              // overlay on xbf+xr
    bf16*  nx    = (bf16*)(ws + 152 * MiB);
    float* Ach   = (float*)(ws + 184 * MiB);
    float* Hla   = (float*)(ws + 185 * MiB);
    float* cyb   = (float*)(ws + 186 * MiB);

    // casts to bf16
    cast_f32_bf16<<<8192, 256, 0, stream>>>(x, xbf, M_ * H_);
    cast_f32_bf16<<<4096, 256, 0, stream>>>(Wxy, wxyb, 2 * R_ * H_);
    cast_f32_bf16<<<2048, 256, 0, stream>>>(Wres, wresb, H_ * R_);

    // GEMM1 split: xr = x*Wxy[0:R]^T ; y = x*Wxy[R:2R]^T
    gemm_bt<bf16><<<dim3(16, 64), 256, 0, stream>>>(xbf, wxyb, xr, 2048, 2048, 2048, 2048);
    gemm_bt<bf16><<<dim3(16, 64), 256, 0, stream>>>(xbf, wxyb + (size_t)R_ * H_, yb,
                                                    2048, 2048, 2048, 2048);

    // causal conv -> xc bf16   (xr dead after this)
    conv_kernel<<<65536, 256, 0, stream>>>(xr, cw, cb, xc);

    // gate prep (runs after GEMM1b so wT can overlay wxyb)
    wcast_T<<<2048, 256, 0, stream>>>(igw, agw, wT);
    sp8_kernel<<<8, 256, 0, stream>>>(apar, sp8);

    // block-diag gates -> a (fp32, overlays xbf+xr), nx (bf16)
    gate_kernel<<<dim3(NB_, 128), 256, 0, stream>>>(xc, wT, igb, agb, sp8, abuf, nx);

    // chunked scan
    scan_passA<<<1024, 256, 0, stream>>>(abuf, nx, Ach, Hla);
    scan_carry<<<16, 256, 0, stream>>>(Ach, Hla, cyb);
    scan_passB<<<1024, 256, 0, stream>>>(abuf, nx, cyb, yb, g);

    // GEMM2: out[M,H] = g[M,R] * Wres[H,R]^T  (fp32 out)
    gemm_bt<float><<<dim3(16, 64), 256, 0, stream>>>(g, wresb, out, 2048, 2048, 2048, 2048);
}

// Round 4
// 501.439 us; speedup vs baseline: 1.3263x; 1.1487x over previous
//
#include <hip/hip_runtime.h>
#include <hip/hip_bf16.h>

typedef __hip_bfloat16 bf16;
typedef __attribute__((ext_vector_type(8))) short s16x8;   // 8 bf16 (4 VGPRs) MFMA frag
typedef __attribute__((ext_vector_type(4))) float f32x4;   // MFMA accumulator

#define B_ 2
#define S_ 4096
#define H_ 2048
#define R_ 2048
#define M_ 8192      // B*S
#define NB_ 16
#define BW_ 128
#define CHUNK 64     // scan chunk length
#define NCH 64       // S/CHUNK

__device__ __forceinline__ short f2b_s(float f) {
    return (short)__builtin_bit_cast(unsigned short, __float2bfloat16(f));
}
__device__ __forceinline__ float b2f_s(short s) {
    unsigned int u = ((unsigned int)(unsigned short)s) << 16;
    return __builtin_bit_cast(float, u);
}
__device__ __forceinline__ float sigm_fast(float x) { return 1.f / (1.f + __expf(-x)); }

// async global->LDS, 16B per lane; LDS dest must be wave-uniform base + lane*16
__device__ __forceinline__ void async_g2l(const void* g, void* l) {
    __builtin_amdgcn_global_load_lds((const __attribute__((address_space(1))) void*)g,
                                     (__attribute__((address_space(3))) void*)l, 16, 0, 0);
}

// ---------------- cast fp32 -> bf16, 8 elems/thread ----------------
__global__ __launch_bounds__(256) void cast_f32_bf16(const float* __restrict__ in,
                                                     bf16* __restrict__ out, int n) {
    int idx = blockIdx.x * 256 + threadIdx.x;
    int i8 = idx * 8;
    if (i8 >= n) return;
    float4 v0 = *(const float4*)(in + i8);
    float4 v1 = *(const float4*)(in + i8 + 4);
    s16x8 o;
    o[0] = f2b_s(v0.x); o[1] = f2b_s(v0.y); o[2] = f2b_s(v0.z); o[3] = f2b_s(v0.w);
    o[4] = f2b_s(v1.x); o[5] = f2b_s(v1.y); o[6] = f2b_s(v1.z); o[7] = f2b_s(v1.w);
    *(s16x8*)(out + i8) = o;
}

// ---------------- transpose-cast gate weights: wT[p][n][j][i] = w_p[n][i][j] ----------
__global__ __launch_bounds__(256) void wcast_T(const float* __restrict__ igw,
                                               const float* __restrict__ agw,
                                               bf16* __restrict__ wT) {
    int idx = blockIdx.x * 256 + threadIdx.x;   // 0 .. 2*NB*128*128
    int p = idx >> 18;
    int rem = idx & 262143;
    int n = rem >> 14;
    int ji = rem & 16383;
    int j = ji >> 7, i = ji & 127;
    const float* w = p ? agw : igw;
    wT[idx] = __float2bfloat16(w[(n << 14) + (i << 7) + j]);
}

// ---------------- sp8[r] = 8*softplus(a_param[r]) ----------------
__global__ __launch_bounds__(256) void sp8_kernel(const float* __restrict__ apar,
                                                  float* __restrict__ sp8) {
    int r = blockIdx.x * 256 + threadIdx.x;
    float ap = apar[r];
    sp8[r] = 8.f * (ap > 20.f ? ap : log1pf(expf(ap)));
}

// ---------------- generic NT GEMM: C[M,N] = A[M,K] * B[N,K]^T, bf16 in, OutT out ----
// 128x128 tile, BK=64, 4 waves 2x2, 64x64/wave, 16x16x32 MFMA, XOR-swizzled LDS,
// global_load_lds width=16 staging (m97 structure). launch_bounds(256,4): 4 blocks/CU.
__device__ __forceinline__ void store_c(float* p, float v) { *p = v; }
__device__ __forceinline__ void store_c(bf16* p, float v) { *p = __float2bfloat16(v); }

template <typename OutT>
__global__ __launch_bounds__(256, 4) void gemm_bt(const bf16* __restrict__ A,
                                                  const bf16* __restrict__ Bm,
                                                  OutT* __restrict__ C,
                                                  int K, int lda, int ldb, int ldc) {
    __shared__ __align__(16) short As[128 * 64];
    __shared__ __align__(16) short Bs[128 * 64];
    const int tid = threadIdx.x;
    const int lane = tid & 63, wave = tid >> 6;
    const int waveM = wave >> 1, waveN = wave & 1;
    const int mBase = blockIdx.y * 128, nBase = blockIdx.x * 128;
    const int fm = lane & 15, q = lane >> 4;

    f32x4 acc[4][4];
#pragma unroll
    for (int i = 0; i < 4; ++i)
#pragma unroll
        for (int j = 0; j < 4; ++j) acc[i][j] = (f32x4){0.f, 0.f, 0.f, 0.f};

    for (int k0 = 0; k0 < K; k0 += 64) {
        __syncthreads();
#pragma unroll
        for (int it = 0; it < 4; ++it) {
            int off = it * 4096 + tid * 16;          // byte offset in tile (lane-contig)
            int r = off >> 7;                        // row
            int g = ((off & 127) >> 4) ^ (r & 7);    // source k-group for this slot
            async_g2l(A + (size_t)(mBase + r) * lda + k0 + g * 8, (char*)As + off);
            async_g2l(Bm + (size_t)(nBase + r) * ldb + k0 + g * 8, (char*)Bs + off);
        }
        __syncthreads();
#pragma unroll
        for (int s = 0; s < 2; ++s) {
            s16x8 af[4], bfr[4];
#pragma unroll
            for (int i = 0; i < 4; ++i) {
                int row = waveM * 64 + i * 16 + fm;
                af[i] = *(const s16x8*)((char*)As + row * 128 + ((((s << 2) + q) ^ (row & 7)) << 4));
                int col = waveN * 64 + i * 16 + fm;
                bfr[i] = *(const s16x8*)((char*)Bs + col * 128 + ((((s << 2) + q) ^ (col & 7)) << 4));
            }
#pragma unroll
            for (int i = 0; i < 4; ++i)
#pragma unroll
                for (int j = 0; j < 4; ++j)
                    acc[i][j] = __builtin_amdgcn_mfma_f32_16x16x32_bf16(af[i], bfr[j], acc[i][j], 0, 0, 0);
        }
    }
    // C/D layout: col=lane&15, row=q*4+reg (m89/m91-verified)
#pragma unroll
    for (int i = 0; i < 4; ++i) {
        int rowg = mBase + waveM * 64 + i * 16 + q * 4;
#pragma unroll
        for (int j = 0; j < 4; ++j) {
            int colg = nBase + waveN * 64 + j * 16 + fm;
#pragma unroll
            for (int rr = 0; rr < 4; ++rr)
                store_c(C + (size_t)(rowg + rr) * ldc + colg, acc[i][j][rr]);
        }
    }
}

// ---------------- causal depthwise conv: xc[m,r] = b[r] + sum_i w[i,r]*xr[m-3+i, r] ----
// xr = columns [0,2048) of xy[M,4096]
__global__ __launch_bounds__(256) void conv_kernel(const bf16* __restrict__ xy,
                                                   const float* __restrict__ cw,
                                                   const float* __restrict__ cb,
                                                   bf16* __restrict__ xc) {
    int idx = blockIdx.x * 256 + threadIdx.x;   // over M_*R_
    int r = idx & (R_ - 1);
    int m = idx >> 11;
    int t = m & (S_ - 1);
    float v = cb[r];
    const bf16* base = xy + (size_t)m * 4096 + r;
#pragma unroll
    for (int i = 0; i < 4; ++i) {
        int tt = t - 3 + i;
        if (tt >= 0) v += cw[i * R_ + r] * __bfloat162float(base[(ptrdiff_t)(i - 3) * 4096]);
    }
    xc[idx] = __float2bfloat16(v);
}

// ---------------- block-diag dual gate GEMM + RG-LRU epilogue + fused chunk scan ------
// grid (NB_, M_/64): one block = one (batch, 64-step chunk, 128-channel block).
// Writes la = log_a (bf16), nx (bf16), and chunk summaries Ach (prod a, fp32) /
// Hla (chunk-local final h, fp32) computed from LDS.
__global__ __launch_bounds__(256) void gate_kernel(const bf16* __restrict__ xc,
                                                   const bf16* __restrict__ wT,
                                                   const float* __restrict__ igb,
                                                   const float* __restrict__ agb,
                                                   const float* __restrict__ sp8,
                                                   bf16* __restrict__ la_out,
                                                   bf16* __restrict__ nx_out,
                                                   float* __restrict__ Ach,
                                                   float* __restrict__ Hla) {
    __shared__ __align__(16) short As[64 * 128];     // 16 KB; xc tile, later nx tile
    __shared__ __align__(16) char  Wmem[128 * 256];  // 32 KB; W tile, later a[64][128] f32
    short* Ws = (short*)Wmem;
    float* a_sh = (float*)Wmem;
    const int n = blockIdx.x;
    const int mBase = blockIdx.y * 64;
    const int tid = threadIdx.x;
    const int lane = tid & 63, wave = tid >> 6;
    const int fm = lane & 15, q = lane >> 4;

    // stage A async: 64 rows x 128 k; slot group gs holds global group gs^(r&15)
#pragma unroll
    for (int it = 0; it < 4; ++it) {
        int off = it * 4096 + tid * 16;
        int r = off >> 8;
        int g = ((off & 255) >> 4) ^ (r & 15);
        async_g2l(xc + (size_t)(mBase + r) * R_ + n * BW_ + g * 8, (char*)As + off);
    }
    // stage Ws for input gate
    const bf16* w0 = wT + (size_t)n * 16384;
#pragma unroll
    for (int it = 0; it < 8; ++it) {
        int off = it * 4096 + tid * 16;
        int j = off >> 8;
        int g = ((off & 255) >> 4) ^ (j & 15);
        async_g2l(w0 + j * 128 + g * 8, (char*)Ws + off);
    }
    __syncthreads();

    f32x4 accI[8], accA[8];
#pragma unroll
    for (int jj = 0; jj < 8; ++jj) {
        accI[jj] = (f32x4){0.f, 0.f, 0.f, 0.f};
        accA[jj] = (f32x4){0.f, 0.f, 0.f, 0.f};
    }

    const int row = wave * 16 + fm;
#pragma unroll
    for (int s = 0; s < 4; ++s) {
        s16x8 af = *(const s16x8*)((char*)As + row * 256 + ((((s << 2) + q) ^ (row & 15)) << 4));
#pragma unroll
        for (int jj = 0; jj < 8; ++jj) {
            int wrow = jj * 16 + fm;
            s16x8 bw = *(const s16x8*)((char*)Ws + wrow * 256 + ((((s << 2) + q) ^ (wrow & 15)) << 4));
            accI[jj] = __builtin_amdgcn_mfma_f32_16x16x32_bf16(af, bw, accI[jj], 0, 0, 0);
        }
    }
    __syncthreads();  // all waves done reading Ws (gate 1)
    // stage Ws for a gate
    const bf16* w1 = wT + (size_t)(NB_ + n) * 16384;
#pragma unroll
    for (int it = 0; it < 8; ++it) {
        int off = it * 4096 + tid * 16;
        int j = off >> 8;
        int g = ((off & 255) >> 4) ^ (j & 15);
        async_g2l(w1 + j * 128 + g * 8, (char*)Ws + off);
    }
    __syncthreads();
#pragma unroll
    for (int s = 0; s < 4; ++s) {
        s16x8 af = *(const s16x8*)((char*)As + row * 256 + ((((s << 2) + q) ^ (row & 15)) << 4));
#pragma unroll
        for (int jj = 0; jj < 8; ++jj) {
            int wrow = jj * 16 + fm;
            s16x8 bw = *(const s16x8*)((char*)Ws + wrow * 256 + ((((s << 2) + q) ^ (wrow & 15)) << 4));
            accA[jj] = __builtin_amdgcn_mfma_f32_16x16x32_bf16(af, bw, accA[jj], 0, 0, 0);
        }
    }
    __syncthreads();  // MFMA reads of As/Ws done; epilogue may overwrite both

    // epilogue: C/D col=fm, row=q*4+rr (tile-local rows 0..63)
    // writes la/nx to global; a (fp32) into a_sh; nx (bf16) back into its own As slot
#pragma unroll
    for (int jj = 0; jj < 8; ++jj) {
        int col = jj * 16 + fm;
        int r = n * BW_ + col;
        float bi = igb[r], ba = agb[r];
        float s8 = sp8[r];
#pragma unroll
        for (int rr = 0; rr < 4; ++rr) {
            int rowl = wave * 16 + q * 4 + rr;
            short* slot = (short*)((char*)As + rowl * 256 +
                          ((((col >> 3)) ^ (rowl & 15)) << 4) + (col & 7) * 2);
            float xcv = b2f_s(*slot);
            float xg = accI[jj][rr] + bi;
            float ag = accA[jj][rr] + ba;
            float la = -s8 * sigm_fast(ag);
            float av = __expf(la);
            float t2 = 2.f * la;
            // -expm1(t2): Taylor for small |t2| (cancellation-safe), else 1 - a^2
            float nem = (t2 > -0.125f)
                ? -t2 * (1.f + t2 * (0.5f + t2 * (0.16666667f + t2 * 0.04166667f)))
                : 1.f - av * av;
            float nxv = xcv * sigm_fast(xg) * sqrtf(nem);
            short nxs = f2b_s(nxv);
            size_t o = (size_t)(mBase + rowl) * R_ + r;
            la_out[o] = __float2bfloat16(la);
            nx_out[o] = __builtin_bit_cast(bf16, (unsigned short)nxs);
            a_sh[rowl * 128 + col] = av;
            *slot = nxs;                       // same slot this thread read; no race
        }
    }
    __syncthreads();

    // fused chunk scan: threads 0..127, one channel each, sequential over 64 rows
    if (tid < 128) {
        int col = tid;
        float h = 0.f, cum = 1.f;
#pragma unroll 4
        for (int t = 0; t < CHUNK; ++t) {
            float a = a_sh[t * 128 + col];
            float nxv = b2f_s(*(const short*)((char*)As + t * 256 +
                              ((((col >> 3)) ^ (t & 15)) << 4) + (col & 7) * 2));
            h = fmaf(a, h, nxv);
            cum *= a;
        }
        int b = mBase >> 12, c = (mBase & (S_ - 1)) >> 6;
        int so = ((b * NCH + c) << 11) + n * BW_ + col;
        Ach[so] = cum;
        Hla[so] = h;
    }
}

// carry into each chunk (sequential over 64 chunks, fp32)
__global__ __launch_bounds__(256) void scan_carry(const float* __restrict__ Ach,
                                                  const float* __restrict__ Hla,
                                                  float* __restrict__ carry) {
    int idx = blockIdx.x * 256 + threadIdx.x;  // B*R
    int r = idx & (R_ - 1), b = idx >> 11;
    float cy = 0.f;
    for (int c = 0; c < NCH; ++c) {
        int o = (b * NCH + c) * R_ + r;
        carry[o] = cy;
        cy = fmaf(Ach[o], cy, Hla[o]);
    }
}

// passB: re-run recurrence with carry folded in; g = gelu_exact(y)*h -> bf16
// y = columns [2048,4096) of xy
__global__ __launch_bounds__(256) void scan_passB(const bf16* __restrict__ la_buf,
                                                  const bf16* __restrict__ nx_buf,
                                                  const float* __restrict__ carry,
                                                  const bf16* __restrict__ xy,
                                                  bf16* __restrict__ g_out) {
    int bid = blockIdx.x;                 // B*NCH*8 = 1024
    int rt = bid & 7, c = (bid >> 3) & 63, b = bid >> 9;
    int r = rt * 256 + threadIdx.x;
    int m0 = b * S_ + c * CHUNK;
    size_t base = (size_t)m0 * R_ + r;
    const bf16* yp = xy + (size_t)m0 * 4096 + 2048 + r;
    int so = (b * NCH + c) * R_ + r;
    float h = carry[so];
    for (int t = 0; t < CHUNK; ++t) {
        size_t o = base + (size_t)t * R_;
        float a = __expf(__bfloat162float(la_buf[o]));
        float nx = __bfloat162float(nx_buf[o]);
        h = fmaf(a, h, nx);
        float y = __bfloat162float(yp[(size_t)t * 4096]);
        float g = 0.5f * y * (1.f + erff(y * 0.70710678f));
        g_out[o] = __float2bfloat16(g * h);
    }
}

extern "C" void kernel_launch(void* const* d_in, const int* in_sizes, int n_in,
                              void* d_out, int out_size, void* d_ws, size_t ws_size,
                              hipStream_t stream) {
    const float* x    = (const float*)d_in[0];
    const float* Wxy  = (const float*)d_in[1];
    const float* igw  = (const float*)d_in[2];
    const float* igb  = (const float*)d_in[3];
    const float* agw  = (const float*)d_in[4];
    const float* agb  = (const float*)d_in[5];
    const float* apar = (const float*)d_in[6];
    const float* cw   = (const float*)d_in[7];
    const float* cb   = (const float*)d_in[8];
    const float* Wres = (const float*)d_in[9];
    float* out = (float*)d_out;

    // Workspace (187 MiB), lifetime overlays:
    //   [0,32)    xbf  bf16 [M,H]   (dead after GEMM1)  -> la bf16 [M,R] (gate output)
    //   [32,48)   wxyb bf16 [2R,H]  (dead after GEMM1)  -> wT (1 MiB) + sp8
    //   [48,112)  xy   bf16 [M,4096] (xr|y); xr dead after conv, y until passB
    //   [112,120) wresb bf16
    //   [120,152) xc   bf16 [M,R]  (dead after gate)    -> g bf16 (passB output)
    //   [152,184) nx   bf16 [M,R]
    //   [184,187) Ach/Hla/carry fp32, 1 MiB each
    char* ws = (char*)d_ws;
    const size_t MiB = (size_t)1 << 20;
    bf16*  xbf   = (bf16*)(ws);
    bf16*  la    = (bf16*)(ws);               // overlay on xbf
    bf16*  wxyb  = (bf16*)(ws + 32 * MiB);
    bf16*  wT    = (bf16*)(ws + 32 * MiB);    // overlay (staged after GEMM1)
    float* sp8   = (float*)(ws + 33 * MiB + 65536);
    bf16*  xy    = (bf16*)(ws + 48 * MiB);
    bf16*  wresb = (bf16*)(ws + 112 * MiB);
    bf16*  xc    = (bf16*)(ws + 120 * MiB);
    bf16*  g     = xc;                        // overlay
    bf16*  nx    = (bf16*)(ws + 152 * MiB);
    float* Ach   = (float*)(ws + 184 * MiB);
    float* Hla   = (float*)(ws + 185 * MiB);
    float* cyb   = (float*)(ws + 186 * MiB);

    // casts to bf16
    cast_f32_bf16<<<8192, 256, 0, stream>>>(x, xbf, M_ * H_);
    cast_f32_bf16<<<4096, 256, 0, stream>>>(Wxy, wxyb, 2 * R_ * H_);
    cast_f32_bf16<<<2048, 256, 0, stream>>>(Wres, wresb, H_ * R_);

    // GEMM1 (merged): xy[M,4096] = x[M,2048] * Wxy[4096,2048]^T
    gemm_bt<bf16><<<dim3(32, 64), 256, 0, stream>>>(xbf, wxyb, xy, 2048, 2048, 2048, 4096);

    // causal conv -> xc bf16   (xr half of xy dead after this)
    conv_kernel<<<65536, 256, 0, stream>>>(xy, cw, cb, xc);

    // gate prep (after GEMM1 so wT/sp8 can overlay wxyb)
    wcast_T<<<2048, 256, 0, stream>>>(igw, agw, wT);
    sp8_kernel<<<8, 256, 0, stream>>>(apar, sp8);

    // gates + fused chunk summaries -> la (overlays xbf), nx, Ach, Hla
    gate_kernel<<<dim3(NB_, 128), 256, 0, stream>>>(xc, wT, igb, agb, sp8, la, nx, Ach, Hla);

    // carry scan + passB -> g (overlays xc)
    scan_carry<<<16, 256, 0, stream>>>(Ach, Hla, cyb);
    scan_passB<<<1024, 256, 0, stream>>>(la, nx, cyb, xy, g);

    // GEMM2: out[M,H] = g[M,R] * Wres[H,R]^T  (fp32 out)
    gemm_bt<float><<<dim3(16, 64), 256, 0, stream>>>(g, wresb, out, 2048, 2048, 2048, 2048);
}